// Round 10
// baseline (82.418 us; speedup 1.0000x reference)
//
#include <hip/hip_runtime.h>
#include <hip/hip_bf16.h>

#define VOCAB 32000
#define EDIM  128
#define QN    32
#define DN    256
#define NK    11
#define REP   4     // instrumentation: repeat identical work to surface rocprof counters

typedef __attribute__((ext_vector_type(8))) short bf16x8;
typedef __attribute__((ext_vector_type(4))) float f32x4;

#define EXP2F(x) __builtin_amdgcn_exp2f(x)

// ---- DPP 16-lane sum (within each aligned group of 16 lanes) ----
template <int CTRL>
static __device__ inline float dpp_add(float x) {
    int y = __builtin_amdgcn_update_dpp(0, __float_as_int(x), CTRL, 0xF, 0xF, true);
    return x + __int_as_float(y);
}
static __device__ inline float sum16(float x) {
    x = dpp_add<0xB1>(x);    // quad_perm xor 1
    x = dpp_add<0x4E>(x);    // quad_perm xor 2
    x = dpp_add<0x124>(x);   // row_ror:4
    x = dpp_add<0x128>(x);   // row_ror:8
    return x;
}

// XOR row swizzle: c = 16B-aligned byte column within a 256B (bf16) row
static __device__ inline int swz(int r, int c) { return c ^ ((r & 7) << 4); }

static __device__ inline bf16x8 pack8(float4 a, float4 b) {
    union { bf16x8 v; __hip_bfloat16 h[8]; } u;
    u.h[0] = __float2bfloat16(a.x); u.h[1] = __float2bfloat16(a.y);
    u.h[2] = __float2bfloat16(a.z); u.h[3] = __float2bfloat16(a.w);
    u.h[4] = __float2bfloat16(b.x); u.h[5] = __float2bfloat16(b.y);
    u.h[6] = __float2bfloat16(b.z); u.h[7] = __float2bfloat16(b.w);
    return u.v;
}

// ---------------- fused kernel (R8 structure) + REP probe loop ----------------
__global__ __launch_bounds__(512, 2) void knrm_fused(const int* __restrict__ qtok,
                                                     const int* __restrict__ dtok,
                                                     const float* __restrict__ emb,
                                                     const float* __restrict__ fcw,
                                                     float* __restrict__ out) {
    __shared__ __align__(16) unsigned short dbuf[DN * EDIM];  // 64 KB
    __shared__ __align__(16) unsigned short qbuf[QN * EDIM];  // 8 KB; overlaid by part[8][16][NK]
    __shared__ int   dtokS[DN];
    __shared__ int   qtokS[QN];
    __shared__ float invS[DN + QN];
    __shared__ float redS[8];

    const float INV_SQRT_2PI = 0.3989422804014327f;
    const float CCH[9] = {8886110.5f, 162754.797f, 2980.95799f, 54.5981500f, 1.0f,
                          0.0183156389f, 3.35462628e-4f, 6.14421235e-6f, 1.12535175e-7f};

    int b = blockIdx.x, tid = threadIdx.x;
    int w = tid >> 6, lane = tid & 63;
    int lr = lane & 15, lg = lane >> 4;

    if (tid < DN) dtokS[tid] = dtok[b * DN + tid];
    else if (tid < DN + QN) qtokS[tid - DN] = qtok[b * QN + (tid - DN)];
    __syncthreads();

    for (int rep = 0; rep < REP; ++rep) {
        asm volatile("" ::: "memory");   // defeat LICM: every rep re-does the work

        // ---- stage rows: 16 lanes x 32B per 512B fp32 row; inline norm; bf16 to LDS ----
        {
            int j = lr, sub = lg;
            {
                int qr = (w << 2) + sub;
                int tok = qtokS[qr];
                const float4* src = (const float4*)(emb + (size_t)tok * EDIM) + j * 2;
                float4 v0 = src[0], v1 = src[1];
                float ss = v0.x * v0.x + v0.y * v0.y + v0.z * v0.z + v0.w * v0.w;
                ss = fmaf(v1.x, v1.x, ss); ss = fmaf(v1.y, v1.y, ss);
                ss = fmaf(v1.z, v1.z, ss); ss = fmaf(v1.w, v1.w, ss);
                float tot = sum16(ss);
                if (j == 0) invS[DN + qr] = 1.0f / sqrtf(tot);
                *(bf16x8*)((char*)qbuf + qr * 256 + swz(qr, j * 16)) = pack8(v0, v1);
            }
            #pragma unroll
            for (int it = 0; it < 8; ++it) {
                int r = (w << 5) + (it << 2) + sub;
                int tok = dtokS[r];
                const float4* src = (const float4*)(emb + (size_t)tok * EDIM) + j * 2;
                float4 v0 = src[0], v1 = src[1];
                float ss = v0.x * v0.x + v0.y * v0.y + v0.z * v0.z + v0.w * v0.w;
                ss = fmaf(v1.x, v1.x, ss); ss = fmaf(v1.y, v1.y, ss);
                ss = fmaf(v1.z, v1.z, ss); ss = fmaf(v1.w, v1.w, ss);
                float tot = sum16(ss);
                if (j == 0) invS[r] = 1.0f / sqrtf(tot);
                *(bf16x8*)((char*)dbuf + r * 256 + swz(r, j * 16)) = pack8(v0, v1);
            }
        }
        __syncthreads();

        int qt = w & 1, ds = w >> 1;

        bf16x8 A0, A1, A2, A3;
        {
            int qr = (qt << 4) + lr;
            const char* qb = (const char*)qbuf + qr * 256;
            A0 = *(const bf16x8*)(qb + swz(qr, lg * 16));
            A1 = *(const bf16x8*)(qb + swz(qr, lg * 16 + 64));
            A2 = *(const bf16x8*)(qb + swz(qr, lg * 16 + 128));
            A3 = *(const bf16x8*)(qb + swz(qr, lg * 16 + 192));
        }
        int   qtr[4];
        float invq[4];
        #pragma unroll
        for (int r = 0; r < 4; ++r) {
            int qrow = (qt << 4) + (lg << 2) + r;
            qtr[r]  = qtokS[qrow];
            invq[r] = invS[DN + qrow];
        }
        __syncthreads();                               // qbuf free for overlay

        float* part = (float*)qbuf;                    // [8][16][NK]

        float kacc[4][NK];
        #pragma unroll
        for (int r = 0; r < 4; ++r)
            #pragma unroll
            for (int k = 0; k < NK; ++k) kacc[r][k] = 0.0f;

        #pragma unroll
        for (int t = 0; t < 4; ++t) {
            int dr = (ds << 6) + (t << 4) + lr;
            const char* db = (const char*)dbuf + dr * 256;
            bf16x8 B0 = *(const bf16x8*)(db + swz(dr, lg * 16));
            bf16x8 B1 = *(const bf16x8*)(db + swz(dr, lg * 16 + 64));
            bf16x8 B2 = *(const bf16x8*)(db + swz(dr, lg * 16 + 128));
            bf16x8 B3 = *(const bf16x8*)(db + swz(dr, lg * 16 + 192));
            int   tcur = dtokS[dr];
            float invd = invS[dr];

            f32x4 acc = {0.0f, 0.0f, 0.0f, 0.0f};
            acc = __builtin_amdgcn_mfma_f32_16x16x32_bf16(A0, B0, acc, 0, 0, 0);
            acc = __builtin_amdgcn_mfma_f32_16x16x32_bf16(A1, B1, acc, 0, 0, 0);
            acc = __builtin_amdgcn_mfma_f32_16x16x32_bf16(A2, B2, acc, 0, 0, 0);
            acc = __builtin_amdgcn_mfma_f32_16x16x32_bf16(A3, B3, acc, 0, 0, 0);

            float sc = (tcur > 0) ? INV_SQRT_2PI : 0.0f;
            #pragma unroll
            for (int r = 0; r < 4; ++r) {
                float t2 = acc[r] * (invq[r] * invd);
                kacc[r][0] += (tcur == qtr[r]) ? sc : 0.0f;
                float s   = fabsf(t2);
                float scP = (t2 >= 0.0f) ? sc : 0.0f;
                float scN = sc - scP;
                float d   = s - 0.9f;
                float g   = EXP2F(d * d * -72.1347520f);
                float E   = EXP2F(s * -28.8539008f);
                #pragma unroll
                for (int m = 1; m <= 10; ++m) {
                    kacc[r][m]      = fmaf(g, scP, kacc[r][m]);
                    kacc[r][11 - m] = fmaf(g, scN, kacc[r][11 - m]);
                    if (m < 10) g = g * E * CCH[m - 1];
                }
            }
        }

        #pragma unroll
        for (int r = 0; r < 4; ++r)
            #pragma unroll
            for (int k = 0; k < NK; ++k) kacc[r][k] = sum16(kacc[r][k]);

        if (lr == 0) {
            float* pw = part + w * (16 * NK) + (lg * 4) * NK;
            #pragma unroll
            for (int r = 0; r < 4; ++r)
                #pragma unroll
                for (int k = 0; k < NK; ++k)
                    pw[r * NK + k] = kacc[r][k];
        }
        __syncthreads();

        float total = 0.0f;
        if (tid < QN * NK) {
            int q = tid / NK, k = tid - (tid / NK) * NK;
            int qt2 = q >> 4, row = q & 15;
            const float* pb = part + qt2 * (16 * NK) + row * NK + k;
            float v = pb[0] + pb[2 * 16 * NK] + pb[4 * 16 * NK] + pb[6 * 16 * NK];
            float m = (qtokS[q] > 0) ? 1.0f : 0.0f;
            total = m * fcw[k] * __logf(fmaxf(v, 1e-10f));
        }
        #pragma unroll
        for (int off = 32; off; off >>= 1) total += __shfl_xor(total, off);
        if (lane == 0) redS[w] = total;
        __syncthreads();
        if (tid == 0) {
            float s = 0.0f;
            #pragma unroll
            for (int i = 0; i < 8; ++i) s += redS[i];
            out[b] = s;
        }
        __syncthreads();   // out/redS settled before next rep re-stages qbuf
    }
}

extern "C" void kernel_launch(void* const* d_in, const int* in_sizes, int n_in,
                              void* d_out, int out_size, void* d_ws, size_t ws_size,
                              hipStream_t stream) {
    const int*   qtok = (const int*)d_in[0];
    const int*   dtok = (const int*)d_in[1];
    const float* emb  = (const float*)d_in[2];
    const float* fcw  = (const float*)d_in[3];
    float* out = (float*)d_out;

    int B = in_sizes[0] / QN;                  // 512
    knrm_fused<<<B, 512, 0, stream>>>(qtok, dtok, emb, fcw, out);
}

// Round 11
// 34.387 us; speedup vs baseline: 2.3968x; 2.3968x over previous
//
#include <hip/hip_runtime.h>
#include <hip/hip_bf16.h>

#define EDIM  128
#define QN    32
#define DN    256
#define DH    128   // docs per half-block
#define NK    11

typedef __attribute__((ext_vector_type(8))) short bf16x8;
typedef __attribute__((ext_vector_type(4))) float f32x4;

#define EXP2F(x) __builtin_amdgcn_exp2f(x)

// ---- DPP 16-lane sum (within each aligned group of 16 lanes) ----
template <int CTRL>
static __device__ inline float dpp_add(float x) {
    int y = __builtin_amdgcn_update_dpp(0, __float_as_int(x), CTRL, 0xF, 0xF, true);
    return x + __int_as_float(y);
}
static __device__ inline float sum16(float x) {
    x = dpp_add<0xB1>(x);    // quad_perm xor 1
    x = dpp_add<0x4E>(x);    // quad_perm xor 2
    x = dpp_add<0x124>(x);   // row_ror:4
    x = dpp_add<0x128>(x);   // row_ror:8
    return x;
}

// XOR row swizzle within a 256B bf16 row
static __device__ inline int swz(int r, int c) { return c ^ ((r & 7) << 4); }

static __device__ inline bf16x8 pack8(float4 a, float4 b) {
    union { bf16x8 v; __hip_bfloat16 h[8]; } u;
    u.h[0] = __float2bfloat16(a.x); u.h[1] = __float2bfloat16(a.y);
    u.h[2] = __float2bfloat16(a.z); u.h[3] = __float2bfloat16(a.w);
    u.h[4] = __float2bfloat16(b.x); u.h[5] = __float2bfloat16(b.y);
    u.h[6] = __float2bfloat16(b.z); u.h[7] = __float2bfloat16(b.w);
    return u.v;
}
static __device__ inline float sumsq8(float4 a, float4 b) {
    float s = a.x * a.x + a.y * a.y + a.z * a.z + a.w * a.w;
    s = fmaf(b.x, b.x, s); s = fmaf(b.y, b.y, s);
    s = fmaf(b.z, b.z, s); s = fmaf(b.w, b.w, s);
    return s;
}

// ---------------- half kernel: one 8-wave block per (batch, 128-doc half) ----------------
__global__ __launch_bounds__(512, 6) void knrm_half(const int* __restrict__ qtok,
                                                    const int* __restrict__ dtok,
                                                    const float* __restrict__ emb,
                                                    float* __restrict__ part) {
    __shared__ __align__(16) unsigned short dbuf[DH * EDIM];  // 32 KB; overlaid by partS after eval
    __shared__ int   dtokS[DH];
    __shared__ int   qtokS[QN];
    __shared__ float invS[DH];

    const float INV_SQRT_2PI = 0.3989422804014327f;

    int bid = blockIdx.x;
    int b = bid >> 1, h = bid & 1;
    int tid = threadIdx.x;
    int w = tid >> 6, lane = tid & 63;
    int lr = lane & 15, lg = lane >> 4;

    if (tid < DH) dtokS[tid] = dtok[b * DN + h * DH + tid];
    else if (tid < DH + QN) qtokS[tid - DH] = qtok[b * QN + (tid - DH)];
    __syncthreads();

    int qt = w & 1, ds = w >> 1;

    // ---- q rows, fp32, register-only: lane holds slices lg*8+s*32 of row qt*16+lr ----
    float4 qv[4][2];
    {
        int tok = qtokS[(qt << 4) + lr];
        const float4* src = (const float4*)(emb + (size_t)tok * EDIM);
        #pragma unroll
        for (int s = 0; s < 4; ++s) {
            qv[s][0] = src[lg * 2 + s * 8];
            qv[s][1] = src[lg * 2 + s * 8 + 1];
        }
    }

    // ---- stage 128 d-rows (16/wave): fp32 load, sumsq, bf16 pack to swizzled LDS ----
    #pragma unroll
    for (int it = 0; it < 4; ++it) {
        int r = (w << 4) + (it << 2) + lg;
        int tok = dtokS[r];
        const float4* src = (const float4*)(emb + (size_t)tok * EDIM) + lr * 2;
        float4 v0 = src[0], v1 = src[1];
        float tot = sum16(sumsq8(v0, v1));
        if (lr == 0) invS[r] = 1.0f / sqrtf(tot);
        *(bf16x8*)((char*)dbuf + r * 256 + swz(r, lr * 16)) = pack8(v0, v1);
    }

    // ---- q norms (cross-slice shfl) + A fragments, all in registers ----
    float ssq = sumsq8(qv[0][0], qv[0][1]) + sumsq8(qv[1][0], qv[1][1]) +
                sumsq8(qv[2][0], qv[2][1]) + sumsq8(qv[3][0], qv[3][1]);
    ssq += __shfl_xor(ssq, 16);
    ssq += __shfl_xor(ssq, 32);
    float myinv = 1.0f / sqrtf(ssq);               // inv-norm of row qt*16+lr
    float invq[4];
    int   qtr[4];
    #pragma unroll
    for (int r = 0; r < 4; ++r) {
        invq[r] = __shfl(myinv, lg * 20 + r);      // lane lg*16 + (lg*4+r)
        qtr[r]  = qtokS[(qt << 4) + (lg << 2) + r];
    }
    bf16x8 A0 = pack8(qv[0][0], qv[0][1]);
    bf16x8 A1 = pack8(qv[1][0], qv[1][1]);
    bf16x8 A2 = pack8(qv[2][0], qv[2][1]);
    bf16x8 A3 = pack8(qv[3][0], qv[3][1]);

    __syncthreads();   // dbuf + invS ready

    float kacc[4][NK];
    #pragma unroll
    for (int r = 0; r < 4; ++r)
        #pragma unroll
        for (int k = 0; k < NK; ++k) kacc[r][k] = 0.0f;

    int xr = (lr & 7) << 4;

    #pragma unroll
    for (int t = 0; t < 2; ++t) {
        int dr = (ds << 5) + (t << 4) + lr;
        const char* db = (const char*)dbuf + dr * 256;
        bf16x8 B0 = *(const bf16x8*)(db + ((lg * 16      ) ^ xr));
        bf16x8 B1 = *(const bf16x8*)(db + ((lg * 16 +  64) ^ xr));
        bf16x8 B2 = *(const bf16x8*)(db + ((lg * 16 + 128) ^ xr));
        bf16x8 B3 = *(const bf16x8*)(db + ((lg * 16 + 192) ^ xr));
        int   tcur = dtokS[dr];
        float invd = invS[dr];

        f32x4 acc = {0.0f, 0.0f, 0.0f, 0.0f};
        acc = __builtin_amdgcn_mfma_f32_16x16x32_bf16(A0, B0, acc, 0, 0, 0);
        acc = __builtin_amdgcn_mfma_f32_16x16x32_bf16(A1, B1, acc, 0, 0, 0);
        acc = __builtin_amdgcn_mfma_f32_16x16x32_bf16(A2, B2, acc, 0, 0, 0);
        acc = __builtin_amdgcn_mfma_f32_16x16x32_bf16(A3, B3, acc, 0, 0, 0);

        float sc = (tcur > 0) ? INV_SQRT_2PI : 0.0f;
        #pragma unroll
        for (int r = 0; r < 4; ++r) {
            float t2 = acc[r] * (invq[r] * invd);
            kacc[r][0] += (tcur == qtr[r]) ? sc : 0.0f;   // K0: exact token match
            // signed center-outward Gaussian chain from mu=0.1 (K5):
            // step m->m+1 factor = e^{-20t} * e^{10(mu_m+mu_{m+1})}
            float d  = t2 - 0.1f;
            float g  = EXP2F(d * d * -72.1347520f);       // K5 = exp(-50(t-0.1)^2)
            float Em = EXP2F(t2 * -28.8539008f);          // e^{-20t}
            float Ep = EXP2F(t2 *  28.8539008f);          // e^{+20t}
            kacc[r][5] = fmaf(g, sc, kacc[r][5]);
            float gd = g * Em;                            // K6 (D=1)
            kacc[r][6] = fmaf(gd, sc, kacc[r][6]);
            gd = gd * Em * 0.0183156389f;                 // K7 (e^-4)
            kacc[r][7] = fmaf(gd, sc, kacc[r][7]);
            gd = gd * Em * 3.35462628e-4f;                // K8 (e^-8)
            kacc[r][8] = fmaf(gd, sc, kacc[r][8]);
            gd = gd * Em * 6.14421235e-6f;                // K9 (e^-12)
            kacc[r][9] = fmaf(gd, sc, kacc[r][9]);
            gd = gd * Em * 1.12535175e-7f;                // K10 (e^-16)
            kacc[r][10] = fmaf(gd, sc, kacc[r][10]);
            float gu = g * Ep * 0.0183156389f;            // K4 (e^-4)
            kacc[r][4] = fmaf(gu, sc, kacc[r][4]);
            gu = gu * Ep * 3.35462628e-4f;                // K3 (e^-8)
            kacc[r][3] = fmaf(gu, sc, kacc[r][3]);
            gu = gu * Ep * 6.14421235e-6f;                // K2 (e^-12)
            kacc[r][2] = fmaf(gu, sc, kacc[r][2]);
            gu = gu * Ep * 1.12535175e-7f;                // K1 (e^-16)
            kacc[r][1] = fmaf(gu, sc, kacc[r][1]);
        }
    }

    // ---- DPP reduce over the 16 doc-columns ----
    #pragma unroll
    for (int r = 0; r < 4; ++r)
        #pragma unroll
        for (int k = 0; k < NK; ++k) kacc[r][k] = sum16(kacc[r][k]);

    __syncthreads();                       // all dbuf reads done
    float* partS = (float*)dbuf;           // overlay: [8][16][NK]
    if (lr == 0) {
        float* pw = partS + (w * 16 + (lg << 2)) * NK;
        #pragma unroll
        for (int r = 0; r < 4; ++r)
            #pragma unroll
            for (int k = 0; k < NK; ++k)
                pw[r * NK + k] = kacc[r][k];
    }
    __syncthreads();

    // ---- combine the 4 doc-spans per q-tile; write global partial [bid][32*NK] ----
    if (tid < 2 * 16 * NK) {               // 352
        int q = tid / NK;
        int k = tid - q * NK;
        int qt2 = q >> 4, row = q & 15;
        float v = 0.0f;
        #pragma unroll
        for (int d2 = 0; d2 < 4; ++d2)
            v += partS[(((d2 << 1) | qt2) * 16 + row) * NK + k];
        part[(size_t)bid * (QN * NK) + tid] = v;
    }
}

// ---------------- final: one block per batch, sum 2 halves + log-pool ----------------
__global__ __launch_bounds__(128) void knrm_reduce(const int* __restrict__ qtok,
                                                   const float* __restrict__ part,
                                                   const float* __restrict__ fcw,
                                                   float* __restrict__ out) {
    __shared__ float red[2];
    int b = blockIdx.x, tid = threadIdx.x;
    const float* p0 = part + (size_t)(b * 2) * (QN * NK);
    const float* p1 = p0 + QN * NK;

    float sum = 0.0f;
    for (int i = tid; i < QN * NK; i += 128) {
        int q = i / NK;
        int k = i - q * NK;
        float v = p0[i] + p1[i];
        float m = (qtok[b * QN + q] > 0) ? 1.0f : 0.0f;
        sum += m * fcw[k] * __logf(fmaxf(v, 1e-10f));
    }
    #pragma unroll
    for (int off = 32; off; off >>= 1) sum += __shfl_xor(sum, off);
    if ((tid & 63) == 0) red[tid >> 6] = sum;
    __syncthreads();
    if (tid == 0) out[b] = red[0] + red[1];
}

extern "C" void kernel_launch(void* const* d_in, const int* in_sizes, int n_in,
                              void* d_out, int out_size, void* d_ws, size_t ws_size,
                              hipStream_t stream) {
    const int*   qtok = (const int*)d_in[0];
    const int*   dtok = (const int*)d_in[1];
    const float* emb  = (const float*)d_in[2];
    const float* fcw  = (const float*)d_in[3];
    float* out  = (float*)d_out;
    float* part = (float*)d_ws;            // 1024 * 352 floats = 1.44 MB

    int B = in_sizes[0] / QN;              // 512
    knrm_half<<<B * 2, 512, 0, stream>>>(qtok, dtok, emb, part);
    knrm_reduce<<<B, 128, 0, stream>>>(qtok, part, fcw, out);
}

// Round 12
// 21.158 us; speedup vs baseline: 3.8952x; 1.6252x over previous
//
#include <hip/hip_runtime.h>
#include <hip/hip_bf16.h>

#define EDIM  128
#define QN    32
#define DN    256
#define NK    11

typedef __attribute__((ext_vector_type(8))) short bf16x8;
typedef __attribute__((ext_vector_type(4))) float f32x4;

#define EXP2F(x) __builtin_amdgcn_exp2f(x)

// ---- DPP 16-lane sum (within each aligned group of 16 lanes) ----
template <int CTRL>
static __device__ inline float dpp_add(float x) {
    int y = __builtin_amdgcn_update_dpp(0, __float_as_int(x), CTRL, 0xF, 0xF, true);
    return x + __int_as_float(y);
}
static __device__ inline float sum16(float x) {
    x = dpp_add<0xB1>(x);    // quad_perm xor 1
    x = dpp_add<0x4E>(x);    // quad_perm xor 2
    x = dpp_add<0x124>(x);   // row_ror:4
    x = dpp_add<0x128>(x);   // row_ror:8
    return x;
}

// XOR row swizzle within a 256B bf16 row
static __device__ inline int swz(int r, int c) { return c ^ ((r & 7) << 4); }

static __device__ inline bf16x8 pack8(float4 a, float4 b) {
    union { bf16x8 v; __hip_bfloat16 h[8]; } u;
    u.h[0] = __float2bfloat16(a.x); u.h[1] = __float2bfloat16(a.y);
    u.h[2] = __float2bfloat16(a.z); u.h[3] = __float2bfloat16(a.w);
    u.h[4] = __float2bfloat16(b.x); u.h[5] = __float2bfloat16(b.y);
    u.h[6] = __float2bfloat16(b.z); u.h[7] = __float2bfloat16(b.w);
    return u.v;
}
static __device__ inline float sumsq8(float4 a, float4 b) {
    float s = a.x * a.x + a.y * a.y + a.z * a.z + a.w * a.w;
    s = fmaf(b.x, b.x, s); s = fmaf(b.y, b.y, s);
    s = fmaf(b.z, b.z, s); s = fmaf(b.w, b.w, s);
    return s;
}

// ---------------- fused kernel: one 8-wave block per batch (R8 base) ----------------
// Split-staged d rows: [0,128) before bar1, [128,256) overlapped with eval tiles 0,1.
// Tile t of wave (qt,ds) covers doc rows t*64 + ds*16 + lr  (t=0,1 entirely in half 1).
__global__ __launch_bounds__(512, 4) void knrm_fused(const int* __restrict__ qtok,
                                                     const int* __restrict__ dtok,
                                                     const float* __restrict__ emb,
                                                     const float* __restrict__ fcw,
                                                     float* __restrict__ out) {
    __shared__ __align__(16) unsigned short dbuf[DN * EDIM];  // 64 KB
    __shared__ __align__(16) unsigned short qbuf[QN * EDIM];  // 8 KB; overlaid by part[8][16][NK]
    __shared__ int   dtokS[DN];
    __shared__ int   qtokS[QN];
    __shared__ float invS[DN + QN];
    __shared__ float redS[8];

    // chain literals: Cj = inv_sqrt_2pi * e^{-4*T(j)}, T = 0,4,12,24,40 cumulative
    const float C0 = 0.3989422804014327f;
    const float C1 = 7.30620157e-3f;    // C0*e^-4
    const float C2 = 2.45119242e-6f;    // C0*e^-12
    const float C3 = 1.50605972e-11f;   // C0*e^-24
    const float C4 = 1.69484929e-18f;   // C0*e^-40

    int b = blockIdx.x, tid = threadIdx.x;
    int w = tid >> 6, lane = tid & 63;
    int lr = lane & 15, lg = lane >> 4;

    if (tid < DN) dtokS[tid] = dtok[b * DN + tid];
    else if (tid < DN + QN) qtokS[tid - DN] = qtok[b * QN + (tid - DN)];
    __syncthreads();                                  // bar0

    // ---- phase A: stage q rows (32) + d rows [0,128); 16 lanes x 32B per row ----
    {
        int qr = (w << 2) + lg;
        int tok = qtokS[qr];
        const float4* src = (const float4*)(emb + (size_t)tok * EDIM) + lr * 2;
        float4 v0 = src[0], v1 = src[1];
        float tot = sum16(sumsq8(v0, v1));
        if (lr == 0) invS[DN + qr] = 1.0f / sqrtf(tot);
        *(bf16x8*)((char*)qbuf + qr * 256 + swz(qr, lr * 16)) = pack8(v0, v1);
    }
    #pragma unroll
    for (int it = 0; it < 4; ++it) {
        int r = (w << 4) + (it << 2) + lg;            // rows [16w, 16w+16)
        int tok = dtokS[r];
        const float4* src = (const float4*)(emb + (size_t)tok * EDIM) + lr * 2;
        float4 v0 = src[0], v1 = src[1];
        float tot = sum16(sumsq8(v0, v1));
        if (lr == 0) invS[r] = 1.0f / sqrtf(tot);
        *(bf16x8*)((char*)dbuf + r * 256 + swz(r, lr * 16)) = pack8(v0, v1);
    }
    __syncthreads();                                  // bar1: half 1 + q ready

    int qt = w & 1, ds = w >> 1;

    // ---- A fragments + per-row q data (reads of half-1 LDS) ----
    bf16x8 A0, A1, A2, A3;
    {
        int qr = (qt << 4) + lr;
        const char* qb = (const char*)qbuf + qr * 256;
        A0 = *(const bf16x8*)(qb + swz(qr, lg * 16));
        A1 = *(const bf16x8*)(qb + swz(qr, lg * 16 + 64));
        A2 = *(const bf16x8*)(qb + swz(qr, lg * 16 + 128));
        A3 = *(const bf16x8*)(qb + swz(qr, lg * 16 + 192));
    }
    int   qtr[4];
    float invq[4];
    #pragma unroll
    for (int r = 0; r < 4; ++r) {
        int qrow = (qt << 4) + (lg << 2) + r;
        qtr[r]  = qtokS[qrow];
        invq[r] = invS[DN + qrow];
    }

    float kacc[4][NK];
    #pragma unroll
    for (int r = 0; r < 4; ++r)
        #pragma unroll
        for (int k = 0; k < NK; ++k) kacc[r][k] = 0.0f;

    // ---- eval one 16x16 tile: doc rows t*64 + ds*16 + lr ----
    auto evalTile = [&](int t) {
        int dr = (t << 6) + (ds << 4) + lr;
        const char* db = (const char*)dbuf + dr * 256;
        bf16x8 B0 = *(const bf16x8*)(db + swz(dr, lg * 16));
        bf16x8 B1 = *(const bf16x8*)(db + swz(dr, lg * 16 + 64));
        bf16x8 B2 = *(const bf16x8*)(db + swz(dr, lg * 16 + 128));
        bf16x8 B3 = *(const bf16x8*)(db + swz(dr, lg * 16 + 192));
        int   tcur = dtokS[dr];
        float invd = invS[dr];

        f32x4 acc = {0.0f, 0.0f, 0.0f, 0.0f};
        acc = __builtin_amdgcn_mfma_f32_16x16x32_bf16(A0, B0, acc, 0, 0, 0);
        acc = __builtin_amdgcn_mfma_f32_16x16x32_bf16(A1, B1, acc, 0, 0, 0);
        acc = __builtin_amdgcn_mfma_f32_16x16x32_bf16(A2, B2, acc, 0, 0, 0);
        acc = __builtin_amdgcn_mfma_f32_16x16x32_bf16(A3, B3, acc, 0, 0, 0);

        bool dok = (tcur > 0);
        float mc = dok ? C0 : 0.0f;                   // K0 literal, d-masked
        #pragma unroll
        for (int r = 0; r < 4; ++r) {
            float t2 = acc[r] * (invq[r] * invd);
            kacc[r][0] += (tcur == qtr[r]) ? mc : 0.0f;   // K0: exact token match
            float d  = t2 - 0.1f;
            float g  = EXP2F(d * d * -72.1347520f);       // exp(-50(t-0.1)^2)
            g = dok ? g : 0.0f;                           // d-mask folded into chain head
            float Em = EXP2F(t2 * -28.8539008f);          // e^{-20t}
            float Ep = EXP2F(t2 *  28.8539008f);          // e^{+20t}
            // center kernel K5 (mu=0.1), then down to K10 and up to K1;
            // cumulative step constants folded into the accumulate literals.
            float h = g;
            kacc[r][5]  += h * C0;
            h *= Em; kacc[r][6]  += h * C0;
            h *= Em; kacc[r][7]  += h * C1;
            h *= Em; kacc[r][8]  += h * C2;
            h *= Em; kacc[r][9]  += h * C3;
            h *= Em; kacc[r][10] += h * C4;
            h = g;
            h *= Ep; kacc[r][4]  += h * C1;
            h *= Ep; kacc[r][3]  += h * C2;
            h *= Ep; kacc[r][2]  += h * C3;
            h *= Ep; kacc[r][1]  += h * C4;
        }
    };

    // ---- phase B: stage d rows [128,256) ; its gather latency overlaps eval t0,t1 ----
    #pragma unroll
    for (int it = 0; it < 4; ++it) {
        int r = 128 + (w << 4) + (it << 2) + lg;
        int tok = dtokS[r];
        const float4* src = (const float4*)(emb + (size_t)tok * EDIM) + lr * 2;
        float4 v0 = src[0], v1 = src[1];
        float tot = sum16(sumsq8(v0, v1));
        if (lr == 0) invS[r] = 1.0f / sqrtf(tot);
        *(bf16x8*)((char*)dbuf + r * 256 + swz(r, lr * 16)) = pack8(v0, v1);
    }
    evalTile(0);
    evalTile(1);
    __syncthreads();                                  // bar2: half 2 ready

    evalTile(2);
    evalTile(3);

    // ---- DPP reduce over the 16 doc-columns; write partial [16][NK] onto qbuf ----
    #pragma unroll
    for (int r = 0; r < 4; ++r)
        #pragma unroll
        for (int k = 0; k < NK; ++k) kacc[r][k] = sum16(kacc[r][k]);

    float* part = (float*)qbuf;                       // safe: qbuf last read before bar2
    if (lr == 0) {
        float* pw = part + w * (16 * NK) + (lg * 4) * NK;
        #pragma unroll
        for (int r = 0; r < 4; ++r)
            #pragma unroll
            for (int k = 0; k < NK; ++k)
                pw[r * NK + k] = kacc[r][k];
    }
    __syncthreads();                                  // bar3: partials visible

    // ---- combine 4 dspans, log-pool, weighted sum -> out[b] ----
    float total = 0.0f;
    if (tid < QN * NK) {
        int q = tid / NK, k = tid - (tid / NK) * NK;
        int qt2 = q >> 4, row = q & 15;
        const float* pb = part + qt2 * (16 * NK) + row * NK + k;
        float v = pb[0] + pb[2 * 16 * NK] + pb[4 * 16 * NK] + pb[6 * 16 * NK];
        float m = (qtokS[q] > 0) ? 1.0f : 0.0f;
        total = m * fcw[k] * __logf(fmaxf(v, 1e-10f));
    }
    #pragma unroll
    for (int off = 32; off; off >>= 1) total += __shfl_xor(total, off);
    if (lane == 0) redS[w] = total;
    __syncthreads();                                  // bar4
    if (tid == 0) {
        float s = 0.0f;
        #pragma unroll
        for (int i = 0; i < 8; ++i) s += redS[i];
        out[b] = s;
    }
}

extern "C" void kernel_launch(void* const* d_in, const int* in_sizes, int n_in,
                              void* d_out, int out_size, void* d_ws, size_t ws_size,
                              hipStream_t stream) {
    const int*   qtok = (const int*)d_in[0];
    const int*   dtok = (const int*)d_in[1];
    const float* emb  = (const float*)d_in[2];
    const float* fcw  = (const float*)d_in[3];
    float* out = (float*)d_out;

    int B = in_sizes[0] / QN;                  // 512
    knrm_fused<<<B, 512, 0, stream>>>(qtok, dtok, emb, fcw, out);
}